// Round 12
// baseline (229.063 us; speedup 1.0000x reference)
//
#include <hip/hip_runtime.h>
#include <math.h>

#define NROWS 65536
#define PER 64
#define BIMG 1024
#define NBLK 512          // 128 rows per block (2 images)
#define NCLS 36
#define OBJ_DIM 192
#define EMB 200
#define POSD 128
#define HID 1024
#define EPSV 1e-5f

#define KP 384            // padded K for GEMM1 (355 real -> 384)
#define XSTR 392          // Xs LDS row stride in fp16 units
#define LSTR 52           // Lst row stride in floats

// X column layout (alignment-friendly; W1 packing permuted to match):
//   [0,192)   features
//   [192,320) pos (relu(h @ pos_W + pos_b))        <- dec1_W rows 392..519
//   [320,355) distribution (folded obj_embed)      <- Fold rows 0..34
//   [355,384) zero pad
//
// W1p fragment-packed layout: idx = ((ht*12 + ks)*64 + lane)*8 + e
//   h = 16*ht + (lane&15), k = 32*ks + 8*(lane>>4) + e
// W2p fragment-packed for mfma_16x16x16f16 B-operand:
//   idx = ((ht*3 + cls)*64 + lane)*4 + e
//   c = 16*cls + (lane&15), h = 16*ht + 4*(lane>>4) + e
//
// R=128 rows/block at the r9 (Wa=4, Wb=2) wave mapping: s = wv&3 hidden slice,
// g = wv>>2 row half (rows 64g..64g+63). Kernel-total A-load instructions HALVE
// vs r9 (768/block, 512 blocks); B ds-read total unchanged; barriers halve.
// C[4][4]+Lg[4][3] = 112 AGPRs -> 2 waves/SIMD (launch_bounds(512,2), no spill).
// GEMM2 in-register; each wave writes disjoint rows of Lst slice s (3 barriers).

typedef __attribute__((ext_vector_type(8))) _Float16 f16x8;
typedef __attribute__((ext_vector_type(4))) _Float16 f16x4;
typedef __attribute__((ext_vector_type(4))) float f32x4;

// ---------------- fold: Fold[35][1024] = obj_embed_W(35x200) @ dec1_W[192:392](200x1024) ----
__global__ __launch_bounds__(256) void k_fold(
    const float* __restrict__ obj_embed_W, const float* __restrict__ dec1_W,
    float* __restrict__ Fold)
{
    int e = blockIdx.x;                               // 0..34
    int h = blockIdx.y * 256 + threadIdx.x;           // 0..1023
    const float* A  = obj_embed_W + (size_t)e * EMB;  // uniform -> s_load
    const float* Bp = dec1_W + (size_t)192 * HID + h;
    float acc = 0.f;
#pragma unroll 8
    for (int j = 0; j < EMB; ++j)
        acc = fmaf(A[j], Bp[(size_t)j * HID], acc);
    Fold[(size_t)e * HID + h] = acc;
}

// ---------------- prep: fragment-packed scaled W1p (fp16), W2p (fp16), bias vector ----------
__global__ __launch_bounds__(256) void k_prep(
    const float* __restrict__ Fold, const float* __restrict__ dec1_W,
    const float* __restrict__ dec1_b,
    const float* __restrict__ bn1k_g, const float* __restrict__ bn1k_b,
    const float* __restrict__ bn1k_m, const float* __restrict__ bn1k_v,
    const float* __restrict__ dec2_W,
    _Float16* __restrict__ W1p, _Float16* __restrict__ W2p,
    float* __restrict__ bs)
{
    int idx = blockIdx.x * 256 + threadIdx.x;
    if (idx < HID * KP) {
        int e  = idx & 7;
        int l  = (idx >> 3) & 63;
        int ks = (idx >> 9) % 12;
        int ht = idx / 6144;
        int h = ht * 16 + (l & 15);
        int k = ks * 32 + (l >> 4) * 8 + e;
        float sc = rsqrtf(bn1k_v[h] + EPSV) * bn1k_g[h];
        float v;
        if (k < 192)      v = dec1_W[(size_t)k * HID + h];
        else if (k < 320) v = dec1_W[(size_t)(k + 200) * HID + h];   // pos rows 392..519
        else if (k < 355) v = Fold[(size_t)(k - 320) * HID + h];     // folded obj_embed
        else              v = 0.f;
        W1p[idx] = (_Float16)(v * sc);
        if (k == 0) bs[h] = (dec1_b[h] - bn1k_m[h]) * sc + bn1k_b[h];  // once per h
    } else {
        int p2 = idx - HID * KP;
        if (p2 < 64 * 3 * 256) {          // 49152
            int e   = p2 & 3;
            int l   = (p2 >> 2) & 63;
            int cls = (p2 >> 8) % 3;
            int ht  = p2 / 768;
            int h = 16 * ht + 4 * (l >> 4) + e;
            int c = 16 * cls + (l & 15);
            W2p[p2] = (c < NCLS) ? (_Float16)dec2_W[(size_t)h * NCLS + c] : (_Float16)0.f;
        }
    }
}

// ---------------- main fused kernel: 128 rows/block, 8 waves (4 slices x 2 row-halves) -----
__global__ __launch_bounds__(512, 2) void k_main(
    const float* __restrict__ distribution, const float* __restrict__ features,
    const float* __restrict__ boxes,
    const float* __restrict__ bn4_g, const float* __restrict__ bn4_b,
    const float* __restrict__ bn4_m, const float* __restrict__ bn4_v,
    const float* __restrict__ pos_W, const float* __restrict__ pos_b,
    const _Float16* __restrict__ W1p, const _Float16* __restrict__ W2p,
    const float* __restrict__ bs, const float* __restrict__ dec2_b,
    float* __restrict__ out)
{
    __shared__ __align__(16) char smem[106496];
    _Float16* Xs = (_Float16*)smem;                // 128*392 fp16 = 100352 B
    float* Lst   = (float*)smem;                   // aliases Xs AFTER compute: 4*128*52*4 = 106496 B

    int t = threadIdx.x;
    int row0 = blockIdx.x * 128;
    int wv = t >> 6, lane = t & 63, lr = lane & 15, lq = lane >> 4;
    int s = wv & 3, g = wv >> 2;

    // ---- stage X as fp16 into Xs, all loads coalesced/vectorized (512 threads) ----
    {
        // features: cols [0,192). 128 rows x 48 float4, fully coalesced, non-temporal.
        const f32x4* F4 = (const f32x4*)(features + (size_t)row0 * OBJ_DIM);
#pragma unroll
        for (int it = 0; it < 12; ++it) {
            int li = t + 512 * it;                 // 0..6143
            int r = li / 48, c4 = li % 48;
            f32x4 v = __builtin_nontemporal_load(F4 + li);
            f16x4 h4;
            h4[0] = (_Float16)v[0]; h4[1] = (_Float16)v[1];
            h4[2] = (_Float16)v[2]; h4[3] = (_Float16)v[3];
            *(f16x4*)&Xs[r * XSTR + c4 * 4] = h4;
        }
        // distribution + zero pad: cols [320,384). 128 rows x 8 groups of 8 = 1024.
        const float* D = distribution + (size_t)row0 * (NCLS - 1);
#pragma unroll
        for (int it = 0; it < 2; ++it) {
            int li = t + 512 * it;                 // 0..1023
            int r = li >> 3, gq = li & 7;
            f16x8 v8;
#pragma unroll
            for (int e = 0; e < 8; ++e) {
                int c = gq * 8 + e;                // 0..63
                v8[e] = (c < 35) ? (_Float16)__builtin_nontemporal_load(D + (size_t)r * 35 + c)
                                 : (_Float16)0.f;
            }
            *(f16x8*)&Xs[r * XSTR + 320 + gq * 8] = v8;
        }
        // pos: cols [192,320). thread (r, kq) computes 32 cols, aligned f16x8 stores.
        int r = t >> 2, kq = t & 3;                // r 0..127, kq 0..3
        int grow = row0 + r;
        const float* bx = boxes + (size_t)grow * 5;
        float x1 = bx[1], y1 = bx[2], x2 = bx[3], y2 = bx[4];
        float w = x2 - x1 + 1.f, hh = y2 - y1 + 1.f;
        float cs[4] = {x1 + 0.5f * w, y1 + 0.5f * hh, w, hh};
        float hv[4];
#pragma unroll
        for (int i = 0; i < 4; i++)
            hv[i] = (cs[i] - bn4_m[i]) * rsqrtf(bn4_v[i] + EPSV) * bn4_g[i] + bn4_b[i];
#pragma unroll
        for (int jb = 0; jb < 4; ++jb) {
            int j0 = kq * 32 + jb * 8;
            f16x8 v8;
#pragma unroll
            for (int e = 0; e < 8; ++e) {
                int j = j0 + e;
                float p = pos_b[j];
                p = fmaf(hv[0], pos_W[j], p);
                p = fmaf(hv[1], pos_W[POSD + j], p);
                p = fmaf(hv[2], pos_W[2 * POSD + j], p);
                p = fmaf(hv[3], pos_W[3 * POSD + j], p);
                v8[e] = (_Float16)fmaxf(p, 0.f);
            }
            *(f16x8*)&Xs[r * XSTR + 192 + j0] = v8;
        }
    }
    __syncthreads();                   // barrier 1 of 3

    f32x4 Lg[4][3];                    // partial logits: rows 64g+16n+4lq+e, c = 16cls+lr
#pragma unroll
    for (int n = 0; n < 4; n++)
#pragma unroll
        for (int cls = 0; cls < 3; cls++) Lg[n][cls] = (f32x4){0.f, 0.f, 0.f, 0.f};

    for (int c0 = 0; c0 < 4; ++c0) {   // hidden chunks of 256 (4 slices x 4 j-tiles)
        // slice's packed A base: ht = 16*c0 + s + 4*j
        const _Float16* ap = W1p + ((size_t)(16 * c0 + s) * 12) * 512 + (size_t)lane * 8;

        f32x4 C[4][4];
#pragma unroll
        for (int j = 0; j < 4; j++)
#pragma unroll
            for (int n = 0; n < 4; n++) C[j][n] = (f32x4){0.f, 0.f, 0.f, 0.f};

        // ---- GEMM1 K-loop: 8 loads / 16 MFMA per step; A-loads lane-contiguous ----
#pragma unroll 2
        for (int ks = 0; ks < 12; ++ks) {
            f16x8 ah[4], bh[4];
#pragma unroll
            for (int j = 0; j < 4; j++)
                ah[j] = *(const f16x8*)(ap + ((size_t)(4 * j) * 12 + ks) * 512);
#pragma unroll
            for (int n = 0; n < 4; n++)
                bh[n] = *(const f16x8*)&Xs[(64 * g + 16 * n + lr) * XSTR + ks * 32 + lq * 8];
#pragma unroll
            for (int j = 0; j < 4; j++)
#pragma unroll
                for (int n = 0; n < 4; n++)
                    C[j][n] = __builtin_amdgcn_mfma_f32_16x16x32_f16(ah[j], bh[n], C[j][n], 0, 0, 0);
        }

        // ---- in-register bias+relu+cvt -> GEMM2 MFMA (no LDS, no barriers) ----
#pragma unroll
        for (int j = 0; j < 4; ++j) {
            int ht = 16 * c0 + s + 4 * j;
            f32x4 bsv = *(const f32x4*)(bs + 16 * ht + 4 * lq);
            f16x4 af[4];
#pragma unroll
            for (int n = 0; n < 4; n++)
#pragma unroll
                for (int e = 0; e < 4; ++e)
                    af[n][e] = (_Float16)fmaxf(C[j][n][e] + bsv[e], 0.f);
#pragma unroll
            for (int cls = 0; cls < 3; ++cls) {
                f16x4 bf = *(const f16x4*)(W2p + ((size_t)(ht * 3 + cls) * 64 + lane) * 4);
#pragma unroll
                for (int n = 0; n < 4; n++)
                    Lg[n][cls] = __builtin_amdgcn_mfma_f32_16x16x16f16(af[n], bf, Lg[n][cls], 0, 0, 0);
            }
        }
    }

    __syncthreads();                   // barrier 2: all Xs reads done; region becomes Lst
    // each wave writes its disjoint rows (g-half) of slice s
    {
        float* Lw = Lst + (size_t)s * 128 * LSTR;
#pragma unroll
        for (int n = 0; n < 4; n++)
#pragma unroll
            for (int cls = 0; cls < 3; cls++)
#pragma unroll
                for (int e = 0; e < 4; ++e)
                    Lw[(64 * g + 16 * n + 4 * lq + e) * LSTR + 16 * cls + lr] = Lg[n][cls][e];
    }
    __syncthreads();                   // barrier 3

    // ---- softmax head + per-image human argmax (t<128: wave 0 -> img 0, wave 1 -> img 1) --
    if (t < 128) {
        int loc = t & 63;              // row within image (wave-local lane)
        int row = row0 + t;
        float lg[36];
#pragma unroll
        for (int c = 1; c < 36; ++c)
            lg[c] = Lst[t * LSTR + c] + Lst[128 * LSTR + t * LSTR + c]
                  + Lst[256 * LSTR + t * LSTR + c] + Lst[384 * LSTR + t * LSTR + c]
                  + dec2_b[c];
        float m = lg[1];
#pragma unroll
        for (int c = 2; c < 36; ++c) m = fmaxf(m, lg[c]);
        float d[35];
        float s2 = 0.f;
#pragma unroll
        for (int c = 1; c < 36; ++c) { float e = expf(lg[c] - m); d[c - 1] = e; s2 += e; }
        float inv = 1.0f / s2;
        float* dout = out + (size_t)row * 35;
#pragma unroll
        for (int j = 0; j < 35; ++j) dout[j] = d[j] * inv;

        // per-row argmax over dist cols 1..34 (first-occurrence), label = distcol+1
        float best = -1.f; int bi = 1;
#pragma unroll
        for (int c = 1; c < 35; ++c) {
            float v = d[c] * inv;
            if (v > best) { best = v; bi = c; }
        }

        // image == wave: argmax over dist[:,0] across the 64 lanes
        float v0 = d[0] * inv;
        float mv = v0; int mi = loc;
#pragma unroll
        for (int off = 32; off > 0; off >>= 1) {
            float ov = __shfl_down(mv, off);
            int   oi = __shfl_down(mi, off);
            if (ov > mv || (ov == mv && oi < mi)) { mv = ov; mi = oi; }
        }
        int human = __shfl(mi, 0);     // local row of the human within this image
        bool isH = (loc == human);
        out[(size_t)NROWS * 35 + row] = isH ? v0 : best;
        out[(size_t)NROWS * 36 + row] = isH ? 1.0f : (float)(bi + 1);
        if (loc == 0)
            out[(size_t)NROWS * 37 + blockIdx.x * 2 + (t >> 6)]
                = (float)(row0 + (t >> 6) * 64 + human);
    }
}

extern "C" void kernel_launch(void* const* d_in, const int* in_sizes, int n_in,
                              void* d_out, int out_size, void* d_ws, size_t ws_size,
                              hipStream_t stream)
{
    (void)in_sizes; (void)n_in; (void)out_size; (void)ws_size;
    const float* distribution = (const float*)d_in[0];
    const float* features     = (const float*)d_in[1];
    const float* boxes        = (const float*)d_in[2];
    const float* obj_embed_W  = (const float*)d_in[3];
    const float* bn4_g        = (const float*)d_in[4];
    const float* bn4_b        = (const float*)d_in[5];
    const float* bn4_m        = (const float*)d_in[6];
    const float* bn4_v        = (const float*)d_in[7];
    const float* pos_W        = (const float*)d_in[8];
    const float* pos_b        = (const float*)d_in[9];
    const float* dec1_W       = (const float*)d_in[10];
    const float* dec1_b       = (const float*)d_in[11];
    const float* bn1k_g       = (const float*)d_in[12];
    const float* bn1k_b       = (const float*)d_in[13];
    const float* bn1k_m       = (const float*)d_in[14];
    const float* bn1k_v       = (const float*)d_in[15];
    const float* dec2_W       = (const float*)d_in[16];
    const float* dec2_b       = (const float*)d_in[17];

    float* out = (float*)d_out;

    // ws layout (~1.01 MB)
    _Float16* W1p  = (_Float16*)d_ws;                      // 1024*384 fp16 (fragment-packed)
    _Float16* W2p  = W1p + (size_t)HID * KP;               // 64*3*256 fp16 (fragment-packed)
    float*    bsv  = (float*)(W2p + (size_t)64 * 3 * 256); // 1024 f32
    float*    Fold = bsv + HID;                            // 35*1024 f32

    k_fold<<<dim3(35, 4), 256, 0, stream>>>(obj_embed_W, dec1_W, Fold);

    int prep_elems = HID * KP + 64 * 3 * 256;              // 442368
    k_prep<<<(prep_elems + 255) / 256, 256, 0, stream>>>(
        Fold, dec1_W, dec1_b, bn1k_g, bn1k_b, bn1k_m, bn1k_v, dec2_W,
        W1p, W2p, bsv);

    k_main<<<NBLK, 512, 0, stream>>>(
        distribution, features, boxes, bn4_g, bn4_b, bn4_m, bn4_v, pos_W, pos_b,
        W1p, W2p, bsv, dec2_b, out);
}

// Round 13
// 207.981 us; speedup vs baseline: 1.1014x; 1.1014x over previous
//
#include <hip/hip_runtime.h>
#include <math.h>

#define NROWS 65536
#define PER 64
#define BIMG 1024
#define NCLS 36
#define OBJ_DIM 192
#define EMB 200
#define POSD 128
#define HID 1024
#define EPSV 1e-5f

#define KP 384            // padded K for GEMM1 (355 real -> 384)
#define XSTR 392          // Xs LDS row stride in fp16 units
#define LSTR 52           // Lst row stride in floats

// X column layout (alignment-friendly; W1 packing permuted to match):
//   [0,192)   features
//   [192,320) pos (relu(h @ pos_W + pos_b))        <- dec1_W rows 392..519
//   [320,355) distribution (folded obj_embed)      <- Fold rows 0..34
//   [355,384) zero pad
//
// W1p fragment-packed layout: idx = ((ht*12 + ks)*64 + lane)*8 + e
//   h = 16*ht + (lane&15), k = 32*ks + 8*(lane>>4) + e
// W2p fragment-packed for mfma_16x16x16f16 B-operand:
//   idx = ((ht*3 + cls)*64 + lane)*4 + e
//   c = 16*cls + (lane&15), h = 16*ht + 4*(lane>>4) + e
//
// PROVEN BEST (round 9, 211.1 us total / k_main 90.5 us): 8 waves/block, hidden
// split into 4 chunks of 256 with C[2][4] per chunk. Wave wv owns ht = 16*c0 +
// wv + 8*j, j in {0,1} — DISJOINT across waves (A-loads never duplicated:
// 768/block, the r10/r12 lesson). GEMM2 in-register (GEMM1 C-fragment layout ==
// mfma_16x16x16f16 A-operand layout); 8 logit partials merged in two LDS
// add-phases (4 barriers total). 12 waves/CU residency; no spill.

typedef __attribute__((ext_vector_type(8))) _Float16 f16x8;
typedef __attribute__((ext_vector_type(4))) _Float16 f16x4;
typedef __attribute__((ext_vector_type(4))) float f32x4;

// ---------------- fold: Fold[35][1024] = obj_embed_W(35x200) @ dec1_W[192:392](200x1024) ----
__global__ __launch_bounds__(256) void k_fold(
    const float* __restrict__ obj_embed_W, const float* __restrict__ dec1_W,
    float* __restrict__ Fold)
{
    int e = blockIdx.x;                               // 0..34
    int h = blockIdx.y * 256 + threadIdx.x;           // 0..1023
    const float* A  = obj_embed_W + (size_t)e * EMB;  // uniform -> s_load
    const float* Bp = dec1_W + (size_t)192 * HID + h;
    float acc = 0.f;
#pragma unroll 8
    for (int j = 0; j < EMB; ++j)
        acc = fmaf(A[j], Bp[(size_t)j * HID], acc);
    Fold[(size_t)e * HID + h] = acc;
}

// ---------------- prep: fragment-packed scaled W1p (fp16), W2p (fp16), bias vector ----------
__global__ __launch_bounds__(256) void k_prep(
    const float* __restrict__ Fold, const float* __restrict__ dec1_W,
    const float* __restrict__ dec1_b,
    const float* __restrict__ bn1k_g, const float* __restrict__ bn1k_b,
    const float* __restrict__ bn1k_m, const float* __restrict__ bn1k_v,
    const float* __restrict__ dec2_W,
    _Float16* __restrict__ W1p, _Float16* __restrict__ W2p,
    float* __restrict__ bs)
{
    int idx = blockIdx.x * 256 + threadIdx.x;
    if (idx < HID * KP) {
        int e  = idx & 7;
        int l  = (idx >> 3) & 63;
        int ks = (idx >> 9) % 12;
        int ht = idx / 6144;
        int h = ht * 16 + (l & 15);
        int k = ks * 32 + (l >> 4) * 8 + e;
        float sc = rsqrtf(bn1k_v[h] + EPSV) * bn1k_g[h];
        float v;
        if (k < 192)      v = dec1_W[(size_t)k * HID + h];
        else if (k < 320) v = dec1_W[(size_t)(k + 200) * HID + h];   // pos rows 392..519
        else if (k < 355) v = Fold[(size_t)(k - 320) * HID + h];     // folded obj_embed
        else              v = 0.f;
        W1p[idx] = (_Float16)(v * sc);
        if (k == 0) bs[h] = (dec1_b[h] - bn1k_m[h]) * sc + bn1k_b[h];  // once per h
    } else {
        int p2 = idx - HID * KP;
        if (p2 < 64 * 3 * 256) {          // 49152
            int e   = p2 & 3;
            int l   = (p2 >> 2) & 63;
            int cls = (p2 >> 8) % 3;
            int ht  = p2 / 768;
            int h = 16 * ht + 4 * (l >> 4) + e;
            int c = 16 * cls + (l & 15);
            W2p[p2] = (c < NCLS) ? (_Float16)dec2_W[(size_t)h * NCLS + c] : (_Float16)0.f;
        }
    }
}

// ---------------- main fused kernel: 64 rows/block, 8 waves, register-lean ------------------
__global__ __launch_bounds__(512, 4) void k_main(
    const float* __restrict__ distribution, const float* __restrict__ features,
    const float* __restrict__ boxes,
    const float* __restrict__ bn4_g, const float* __restrict__ bn4_b,
    const float* __restrict__ bn4_m, const float* __restrict__ bn4_v,
    const float* __restrict__ pos_W, const float* __restrict__ pos_b,
    const _Float16* __restrict__ W1p, const _Float16* __restrict__ W2p,
    const float* __restrict__ bs, const float* __restrict__ dec2_b,
    float* __restrict__ out)
{
    __shared__ __align__(16) char smem[53248];
    _Float16* Xs = (_Float16*)smem;                // 64*392 fp16 = 50176 B
    float* Lst   = (float*)smem;                   // aliases Xs AFTER compute: 4*64*52*4 = 53248 B

    int t = threadIdx.x;
    int row0 = blockIdx.x * PER;
    int wv = t >> 6, lane = t & 63, lr = lane & 15, lq = lane >> 4;

    // ---- stage X as fp16 into Xs, all loads coalesced/vectorized (512 threads) ----
    {
        // features: cols [0,192). 64 rows x 48 float4, fully coalesced, non-temporal.
        const f32x4* F4 = (const f32x4*)(features + (size_t)row0 * OBJ_DIM);
#pragma unroll
        for (int it = 0; it < 6; ++it) {
            int li = t + 512 * it;                 // 0..3071
            int r = li / 48, c4 = li % 48;
            f32x4 v = __builtin_nontemporal_load(F4 + li);
            f16x4 h4;
            h4[0] = (_Float16)v[0]; h4[1] = (_Float16)v[1];
            h4[2] = (_Float16)v[2]; h4[3] = (_Float16)v[3];
            *(f16x4*)&Xs[r * XSTR + c4 * 4] = h4;
        }
        // distribution + zero pad: cols [320,384). 64 rows x 8 groups of 8 = 512.
        const float* D = distribution + (size_t)row0 * (NCLS - 1);
        {
            int r = t >> 3, gq = t & 7;
            f16x8 v8;
#pragma unroll
            for (int e = 0; e < 8; ++e) {
                int c = gq * 8 + e;                // 0..63
                v8[e] = (c < 35) ? (_Float16)__builtin_nontemporal_load(D + (size_t)r * 35 + c)
                                 : (_Float16)0.f;
            }
            *(f16x8*)&Xs[r * XSTR + 320 + gq * 8] = v8;
        }
        // pos: cols [192,320). thread (r, kq) computes 16 cols, aligned f16x8 stores.
        int r = t >> 3, kq = t & 7;
        int grow = row0 + r;
        const float* bx = boxes + (size_t)grow * 5;
        float x1 = bx[1], y1 = bx[2], x2 = bx[3], y2 = bx[4];
        float w = x2 - x1 + 1.f, hh = y2 - y1 + 1.f;
        float cs[4] = {x1 + 0.5f * w, y1 + 0.5f * hh, w, hh};
        float hv[4];
#pragma unroll
        for (int i = 0; i < 4; i++)
            hv[i] = (cs[i] - bn4_m[i]) * rsqrtf(bn4_v[i] + EPSV) * bn4_g[i] + bn4_b[i];
#pragma unroll
        for (int jb = 0; jb < 2; ++jb) {
            int j0 = kq * 16 + jb * 8;
            f16x8 v8;
#pragma unroll
            for (int e = 0; e < 8; ++e) {
                int j = j0 + e;
                float p = pos_b[j];
                p = fmaf(hv[0], pos_W[j], p);
                p = fmaf(hv[1], pos_W[POSD + j], p);
                p = fmaf(hv[2], pos_W[2 * POSD + j], p);
                p = fmaf(hv[3], pos_W[3 * POSD + j], p);
                v8[e] = (_Float16)fmaxf(p, 0.f);
            }
            *(f16x8*)&Xs[r * XSTR + 192 + j0] = v8;
        }
    }
    __syncthreads();                   // barrier 1 of 4

    f32x4 Lg[4][3];                    // partial logits: rows 16n+4lq+e, c = 16cls+lr
#pragma unroll
    for (int n = 0; n < 4; n++)
#pragma unroll
        for (int cls = 0; cls < 3; cls++) Lg[n][cls] = (f32x4){0.f, 0.f, 0.f, 0.f};

    for (int c0 = 0; c0 < 4; ++c0) {   // hidden chunks of 256 (8 waves x 2 j-tiles)
        // wave's packed A base: ht = 16*c0 + wv + 8*j  (disjoint across waves)
        const _Float16* ap = W1p + ((size_t)(16 * c0 + wv) * 12) * 512 + (size_t)lane * 8;

        f32x4 C[2][4];
#pragma unroll
        for (int j = 0; j < 2; j++)
#pragma unroll
            for (int n = 0; n < 4; n++) C[j][n] = (f32x4){0.f, 0.f, 0.f, 0.f};

        // ---- GEMM1 K-loop: 6 loads / 8 MFMA per step; A-loads lane-contiguous ----
#pragma unroll 4
        for (int ks = 0; ks < 12; ++ks) {
            f16x8 ah[2], bh[4];
#pragma unroll
            for (int j = 0; j < 2; j++)
                ah[j] = *(const f16x8*)(ap + ((size_t)(8 * j) * 12 + ks) * 512);
#pragma unroll
            for (int n = 0; n < 4; n++)
                bh[n] = *(const f16x8*)&Xs[(16 * n + lr) * XSTR + ks * 32 + lq * 8];
#pragma unroll
            for (int j = 0; j < 2; j++)
#pragma unroll
                for (int n = 0; n < 4; n++)
                    C[j][n] = __builtin_amdgcn_mfma_f32_16x16x32_f16(ah[j], bh[n], C[j][n], 0, 0, 0);
        }

        // ---- in-register bias+relu+cvt -> GEMM2 MFMA (no LDS, no barriers) ----
#pragma unroll
        for (int j = 0; j < 2; ++j) {
            int ht = 16 * c0 + wv + 8 * j;
            f32x4 bsv = *(const f32x4*)(bs + 16 * ht + 4 * lq);
            f16x4 af[4];
#pragma unroll
            for (int n = 0; n < 4; n++)
#pragma unroll
                for (int e = 0; e < 4; ++e)
                    af[n][e] = (_Float16)fmaxf(C[j][n][e] + bsv[e], 0.f);
#pragma unroll
            for (int cls = 0; cls < 3; ++cls) {
                f16x4 bf = *(const f16x4*)(W2p + ((size_t)(ht * 3 + cls) * 64 + lane) * 4);
#pragma unroll
                for (int n = 0; n < 4; n++)
                    Lg[n][cls] = __builtin_amdgcn_mfma_f32_16x16x16f16(af[n], bf, Lg[n][cls], 0, 0, 0);
            }
        }
    }

    __syncthreads();                   // barrier 2: all Xs reads done; region becomes Lst
    // merge 8 wave-partials into 4 slices: waves 0-3 write, waves 4-7 add.
    {
        float* Lw = Lst + (size_t)(wv & 3) * 64 * LSTR;
        if (wv < 4) {
#pragma unroll
            for (int n = 0; n < 4; n++)
#pragma unroll
                for (int cls = 0; cls < 3; cls++)
#pragma unroll
                    for (int e = 0; e < 4; ++e)
                        Lw[(16 * n + 4 * lq + e) * LSTR + 16 * cls + lr] = Lg[n][cls][e];
        }
        __syncthreads();               // barrier 3
        if (wv >= 4) {
#pragma unroll
            for (int n = 0; n < 4; n++)
#pragma unroll
                for (int cls = 0; cls < 3; cls++)
#pragma unroll
                    for (int e = 0; e < 4; ++e)
                        Lw[(16 * n + 4 * lq + e) * LSTR + 16 * cls + lr] += Lg[n][cls][e];
        }
    }
    __syncthreads();                   // barrier 4

    // ---- softmax head + fused per-image human argmax (t<64 == wave 0) ----
    if (t < 64) {
        int row = row0 + t;
        float lg[36];
#pragma unroll
        for (int c = 1; c < 36; ++c)
            lg[c] = Lst[t * LSTR + c] + Lst[64 * LSTR + t * LSTR + c]
                  + Lst[128 * LSTR + t * LSTR + c] + Lst[192 * LSTR + t * LSTR + c]
                  + dec2_b[c];
        float m = lg[1];
#pragma unroll
        for (int c = 2; c < 36; ++c) m = fmaxf(m, lg[c]);
        float d[35];
        float s2 = 0.f;
#pragma unroll
        for (int c = 1; c < 36; ++c) { float e = expf(lg[c] - m); d[c - 1] = e; s2 += e; }
        float inv = 1.0f / s2;
        float* dout = out + (size_t)row * 35;
#pragma unroll
        for (int j = 0; j < 35; ++j) dout[j] = d[j] * inv;

        // per-row argmax over dist cols 1..34 (first-occurrence), label = distcol+1
        float best = -1.f; int bi = 1;
#pragma unroll
        for (int c = 1; c < 35; ++c) {
            float v = d[c] * inv;
            if (v > best) { best = v; bi = c; }
        }

        // block == image: argmax over dist[:,0] across the 64 lanes
        float v0 = d[0] * inv;
        float mv = v0; int mi = t;
#pragma unroll
        for (int off = 32; off > 0; off >>= 1) {
            float ov = __shfl_down(mv, off);
            int   oi = __shfl_down(mi, off);
            if (ov > mv || (ov == mv && oi < mi)) { mv = ov; mi = oi; }
        }
        int human = __shfl(mi, 0);     // local row of the human
        bool isH = (t == human);
        out[(size_t)NROWS * 35 + row] = isH ? v0 : best;
        out[(size_t)NROWS * 36 + row] = isH ? 1.0f : (float)(bi + 1);
        if (t == 0) out[(size_t)NROWS * 37 + blockIdx.x] = (float)(row0 + human);
    }
}

extern "C" void kernel_launch(void* const* d_in, const int* in_sizes, int n_in,
                              void* d_out, int out_size, void* d_ws, size_t ws_size,
                              hipStream_t stream)
{
    (void)in_sizes; (void)n_in; (void)out_size; (void)ws_size;
    const float* distribution = (const float*)d_in[0];
    const float* features     = (const float*)d_in[1];
    const float* boxes        = (const float*)d_in[2];
    const float* obj_embed_W  = (const float*)d_in[3];
    const float* bn4_g        = (const float*)d_in[4];
    const float* bn4_b        = (const float*)d_in[5];
    const float* bn4_m        = (const float*)d_in[6];
    const float* bn4_v        = (const float*)d_in[7];
    const float* pos_W        = (const float*)d_in[8];
    const float* pos_b        = (const float*)d_in[9];
    const float* dec1_W       = (const float*)d_in[10];
    const float* dec1_b       = (const float*)d_in[11];
    const float* bn1k_g       = (const float*)d_in[12];
    const float* bn1k_b       = (const float*)d_in[13];
    const float* bn1k_m       = (const float*)d_in[14];
    const float* bn1k_v       = (const float*)d_in[15];
    const float* dec2_W       = (const float*)d_in[16];
    const float* dec2_b       = (const float*)d_in[17];

    float* out = (float*)d_out;

    // ws layout (~1.01 MB)
    _Float16* W1p  = (_Float16*)d_ws;                      // 1024*384 fp16 (fragment-packed)
    _Float16* W2p  = W1p + (size_t)HID * KP;               // 64*3*256 fp16 (fragment-packed)
    float*    bsv  = (float*)(W2p + (size_t)64 * 3 * 256); // 1024 f32
    float*    Fold = bsv + HID;                            // 35*1024 f32

    k_fold<<<dim3(35, 4), 256, 0, stream>>>(obj_embed_W, dec1_W, Fold);

    int prep_elems = HID * KP + 64 * 3 * 256;              // 442368
    k_prep<<<(prep_elems + 255) / 256, 256, 0, stream>>>(
        Fold, dec1_W, dec1_b, bn1k_g, bn1k_b, bn1k_m, bn1k_v, dec2_W,
        W1p, W2p, bsv);

    k_main<<<BIMG, 512, 0, stream>>>(
        distribution, features, boxes, bn4_g, bn4_b, bn4_m, bn4_v, pos_W, pos_b,
        W1p, W2p, bsv, dec2_b, out);
}